// Round 9
// baseline (151.252 us; speedup 1.0000x reference)
//
#include <hip/hip_runtime.h>
#include <cmath>

#define BB   512
#define NSV  128
#define NTRK 512
#define KK   8
#define HH   16
#define TPB  512
#define RSTR 20            // LDS row stride: [16 feats][0.5*||sv||^2][pad x3] (80B -> 16B-aligned quads)
#define PSTR 20            // padded proj stride in LDS

__device__ __forceinline__ float elu_f(float x) {
    return x > 0.0f ? x : expm1f(x);
}
__device__ __forceinline__ unsigned umin_u(unsigned a, unsigned b) { return a < b ? a : b; }
__device__ __forceinline__ unsigned med3u(unsigned a, unsigned b, unsigned c) {
    unsigned d;
    asm("v_med3_u32 %0, %1, %2, %3" : "=v"(d) : "v"(a), "v"(b), "v"(c));
    return d;
}
// broadcast lane `l`'s copy of x to all lanes (result is wave-uniform -> SGPR)
#define RL(x, l) __uint_as_float((unsigned)__builtin_amdgcn_readlane((int)__float_as_uint(x), (l)))

// Single fused kernel, no global workspace. Block b owns batch b:
//  phase A: SV MLP -> rows in LDS; proj -> LDS; u/c0 -> LDS
//  phase B: track MLP (all 512 threads)
//  barrier; each lane pulls rows (lane, lane+64) into registers
//  scan: per-row broadcast via v_readlane (zero in-loop memory traffic)
__global__ __launch_bounds__(TPB, 4) void fused_all(
    const float* __restrict__ x_sv, const float* __restrict__ x_trk,
    const float* __restrict__ W1s, const float* __restrict__ b1s,
    const float* __restrict__ W2s, const float* __restrict__ b2s,
    const float* __restrict__ W1t, const float* __restrict__ b1t,
    const float* __restrict__ W2t, const float* __restrict__ b2t,
    const float* __restrict__ We,  const float* __restrict__ be,
    const float* __restrict__ Wo,  const float* __restrict__ bo,
    float* __restrict__ out)
{
    __shared__ float rowS[NSV][RSTR];    // SV rows: feats + half-sq
    __shared__ float proj[NSV][PSTR];
    __shared__ float ucS[HH + 1];        // u[16], c0
    __shared__ float sred[TPB / 64];

    const int b = blockIdx.x, tid = threadIdx.x;

    // ---- phase A ----
    if (tid < NSV) {
        const float* xp = x_sv + (size_t)(b * NSV + tid) * 2;
        float x0 = xp[0], x1 = xp[1];
        float hb[HH];
        #pragma unroll
        for (int h = 0; h < HH; ++h)
            hb[h] = elu_f(x0 * W1s[h] + x1 * W1s[HH + h] + b1s[h]);
        float o[HH], sq = 0.0f;
        #pragma unroll
        for (int h2 = 0; h2 < HH; ++h2) {
            float a = b2s[h2];
            #pragma unroll
            for (int h = 0; h < HH; ++h) a += hb[h] * W2s[h * HH + h2];
            o[h2] = a;
            sq += a * a;
        }
        #pragma unroll
        for (int h = 0; h < HH; ++h) rowS[tid][h] = o[h];
        rowS[tid][HH] = 0.5f * sq;
        // proj[s][h] = o . We_bot[:,h]
        #pragma unroll
        for (int h = 0; h < HH; ++h) {
            float a = 0.0f;
            #pragma unroll
            for (int j = 0; j < HH; ++j) a += o[j] * We[(HH + j) * HH + h];
            proj[tid][h] = a;
        }
    } else if (tid < NSV + HH) {
        int j = tid - NSV;               // u[j] = sum_h Wdiff[j][h]*Wo[h]
        float a = 0.0f;
        #pragma unroll
        for (int h = 0; h < HH; ++h)
            a += (We[j * HH + h] - We[(HH + j) * HH + h]) * Wo[h];
        ucS[j] = a;
    } else if (tid == NSV + HH) {
        float a = bo[0];
        #pragma unroll
        for (int h = 0; h < HH; ++h) a += be[h] * Wo[h];
        ucS[HH] = a;
    }

    // ---- phase B: track MLP (uniform weights -> scalar loads) ----
    float tf[HH], htsq;
    {
        const float* xp = x_trk + (size_t)(b * NTRK + tid) * 8;
        float x[8];
        *(float4*)&x[0] = *(const float4*)&xp[0];
        *(float4*)&x[4] = *(const float4*)&xp[4];
        float hb[HH];
        #pragma unroll
        for (int h = 0; h < HH; ++h) {
            float a = b1t[h];
            #pragma unroll
            for (int i = 0; i < 8; ++i) a += x[i] * W1t[i * HH + h];
            hb[h] = elu_f(a);
        }
        float sq = 0.0f;
        #pragma unroll
        for (int h2 = 0; h2 < HH; ++h2) {
            float a = b2t[h2];
            #pragma unroll
            for (int h = 0; h < HH; ++h) a += hb[h] * W2t[h * HH + h2];
            tf[h2] = a;
            sq += a * a;
        }
        htsq = 0.5f * sq;
    }

    unsigned k[KK];
    #pragma unroll
    for (int q = 0; q < KK; ++q) k[q] = 0xFFFFFFFFu;

    __syncthreads();   // rows/proj/uc staged

    // ---- pull 2 rows per lane into registers (one-time LDS reads) ----
    const int lane = tid & 63;
    float rA[17], rB[17];
    #pragma unroll
    for (int j4 = 0; j4 < 4; ++j4) {
        float4 a4 = *(const float4*)&rowS[lane][j4 * 4];
        float4 b4 = *(const float4*)&rowS[lane + 64][j4 * 4];
        rA[j4*4+0] = a4.x; rA[j4*4+1] = a4.y; rA[j4*4+2] = a4.z; rA[j4*4+3] = a4.w;
        rB[j4*4+0] = b4.x; rB[j4*4+1] = b4.y; rB[j4*4+2] = b4.z; rB[j4*4+3] = b4.w;
    }
    rA[16] = rowS[lane][HH];
    rB[16] = rowS[lane + 64][HH];

    // ---- kNN scan: readlane broadcast, zero in-loop memory ----
    #define SCAN(R, base)                                                   \
        _Pragma("unroll 8")                                                 \
        for (int s = 0; s < 64; ++s) {                                      \
            float u[17];                                                    \
            _Pragma("unroll")                                               \
            for (int j = 0; j < 17; ++j) u[j] = RL(R[j], s);                \
            float a0 = -tf[0] * u[0];                                       \
            float a1 = -tf[1] * u[1];                                       \
            float a2 = -tf[2] * u[2];                                       \
            float a3 = -tf[3] * u[3];                                       \
            _Pragma("unroll")                                               \
            for (int j = 4; j < 16; j += 4) {                               \
                a0 = fmaf(-tf[j],     u[j],     a0);                        \
                a1 = fmaf(-tf[j + 1], u[j + 1], a1);                        \
                a2 = fmaf(-tf[j + 2], u[j + 2], a2);                        \
                a3 = fmaf(-tf[j + 3], u[j + 3], a3);                        \
            }                                                               \
            float e = fmaxf(((htsq + u[16]) + (a0 + a1)) + (a2 + a3), 0.0f);\
            unsigned v = (__float_as_uint(e) & 0xFFFFFF80u)                 \
                         | (unsigned)((base) + s);                          \
            unsigned nk0 = umin_u(v, k[0]);                                 \
            unsigned nk1 = med3u(v, k[0], k[1]);                            \
            unsigned nk2 = med3u(v, k[1], k[2]);                            \
            unsigned nk3 = med3u(v, k[2], k[3]);                            \
            unsigned nk4 = med3u(v, k[3], k[4]);                            \
            unsigned nk5 = med3u(v, k[4], k[5]);                            \
            unsigned nk6 = med3u(v, k[5], k[6]);                            \
            unsigned nk7 = med3u(v, k[6], k[7]);                            \
            k[0] = nk0; k[1] = nk1; k[2] = nk2; k[3] = nk3;                 \
            k[4] = nk4; k[5] = nk5; k[6] = nk6; k[7] = nk7;                 \
        }

    SCAN(rA, 0)
    SCAN(rB, 64)
    #undef SCAN

    // ---- epilogue: acc = c0 + tf.u + sum_h max_k(proj)[h]*Wo[h] ----
    float local;
    {
        float acc = ucS[HH];
        #pragma unroll
        for (int j = 0; j < HH; ++j) acc = fmaf(tf[j], ucS[j], acc);

        float mx[HH];
        #pragma unroll
        for (int h = 0; h < HH; ++h) mx[h] = -INFINITY;
        #pragma unroll
        for (int q = 0; q < KK; ++q) {
            const float* pr = &proj[k[q] & 127u][0];
            #pragma unroll
            for (int h4 = 0; h4 < 4; ++h4) {
                float4 p = *(const float4*)&pr[h4 * 4];
                mx[h4 * 4 + 0] = fmaxf(mx[h4 * 4 + 0], p.x);
                mx[h4 * 4 + 1] = fmaxf(mx[h4 * 4 + 1], p.y);
                mx[h4 * 4 + 2] = fmaxf(mx[h4 * 4 + 2], p.z);
                mx[h4 * 4 + 3] = fmaxf(mx[h4 * 4 + 3], p.w);
            }
        }
        #pragma unroll
        for (int h = 0; h < HH; ++h) acc = fmaf(mx[h], Wo[h], acc);
        local = 1.0f / (1.0f + expf(-acc));
    }

    // ---- block mean-pool ----
    #pragma unroll
    for (int off = 32; off > 0; off >>= 1)
        local += __shfl_down(local, off, 64);
    if ((tid & 63) == 0) sred[tid >> 6] = local;
    __syncthreads();
    if (tid == 0) {
        float tot = 0.0f;
        #pragma unroll
        for (int w = 0; w < TPB / 64; ++w) tot += sred[w];
        out[b]      = tot * (1.0f / NTRK);
        out[BB + b] = (float)b;
    }
}

extern "C" void kernel_launch(void* const* d_in, const int* in_sizes, int n_in,
                              void* d_out, int out_size, void* d_ws, size_t ws_size,
                              hipStream_t stream) {
    const float* x_sv  = (const float*)d_in[0];
    const float* x_trk = (const float*)d_in[1];
    const float* W1s = (const float*)d_in[4];
    const float* b1s = (const float*)d_in[5];
    const float* W2s = (const float*)d_in[6];
    const float* b2s = (const float*)d_in[7];
    const float* W1t = (const float*)d_in[8];
    const float* b1t = (const float*)d_in[9];
    const float* W2t = (const float*)d_in[10];
    const float* b2t = (const float*)d_in[11];
    const float* We  = (const float*)d_in[12];
    const float* be  = (const float*)d_in[13];
    const float* Wo  = (const float*)d_in[14];
    const float* bo  = (const float*)d_in[15];
    float* out = (float*)d_out;

    fused_all<<<BB, TPB, 0, stream>>>(x_sv, x_trk,
                                      W1s, b1s, W2s, b2s,
                                      W1t, b1t, W2t, b2t,
                                      We, be, Wo, bo, out);
}

// Round 10
// 131.076 us; speedup vs baseline: 1.1539x; 1.1539x over previous
//
#include <hip/hip_runtime.h>
#include <cmath>

#define BB   512
#define NSV  128
#define NTRK 512
#define KK   8
#define HH   16
#define TPB  1024          // 2 threads per track (halves of the SV scan)
#define RSTR 20            // global row stride: [16 feats][0.5*||sv||^2][pad x3]
#define PSTR 20            // padded proj stride in LDS
#define KSTR 17            // padded key-buffer stride (odd -> conflict-free)

typedef float vf2 __attribute__((ext_vector_type(2)));

__device__ __forceinline__ float elu_f(float x) {
    return x > 0.0f ? x : expm1f(x);
}
__device__ __forceinline__ unsigned umin_u(unsigned a, unsigned b) { return a < b ? a : b; }
__device__ __forceinline__ unsigned med3u(unsigned a, unsigned b, unsigned c) {
    unsigned d;
    asm("v_med3_u32 %0, %1, %2, %3" : "=v"(d) : "v"(a), "v"(b), "v"(c));
    return d;
}

// One block = one batch. 1024 threads: thread tid handles track (tid&511),
// scanning SV half (tid>>9). Rows round-trip through global (block-local,
// L2-hot) to ride the scalar-load path; halves merge top-8 lists in LDS.
__global__ __launch_bounds__(TPB, 8) void fused_all(
    const float* __restrict__ x_sv, const float* __restrict__ x_trk,
    const float* __restrict__ W1s, const float* __restrict__ b1s,
    const float* __restrict__ W2s, const float* __restrict__ b2s,
    const float* __restrict__ W1t, const float* __restrict__ b1t,
    const float* __restrict__ W2t, const float* __restrict__ b2t,
    const float* __restrict__ We,  const float* __restrict__ be,
    const float* __restrict__ Wo,  const float* __restrict__ bo,
    float* __restrict__ svw,             // ws rows, write alias
    const float* __restrict__ svr,       // ws rows, read alias (scalar loads)
    float* __restrict__ out)
{
    __shared__ float    proj[NSV][PSTR];
    __shared__ unsigned kbuf[NTRK][KSTR];   // [track][half*8+q]
    __shared__ float    ucS[HH + 1];        // u[16], c0
    __shared__ float    sred[TPB / 64];

    const int b   = blockIdx.x, tid = threadIdx.x;
    const int tl  = tid & 511;                                    // track
    const int sh  = __builtin_amdgcn_readfirstlane(tid >> 9);     // 0/1, wave-uniform

    // ---- phase A: SV MLP -> global rows + LDS proj; u/c0 ----
    if (tid < NSV) {
        const float* xp = x_sv + (size_t)(b * NSV + tid) * 2;
        float x0 = xp[0], x1 = xp[1];
        float hb[HH];
        #pragma unroll
        for (int h = 0; h < HH; ++h)
            hb[h] = elu_f(x0 * W1s[h] + x1 * W1s[HH + h] + b1s[h]);
        float o[HH], sq = 0.0f;
        #pragma unroll
        for (int h2 = 0; h2 < HH; ++h2) {
            float a = b2s[h2];
            #pragma unroll
            for (int h = 0; h < HH; ++h) a += hb[h] * W2s[h * HH + h2];
            o[h2] = a;
            sq += a * a;
        }
        float* dst = svw + (size_t)(b * NSV + tid) * RSTR;
        #pragma unroll
        for (int h4 = 0; h4 < 4; ++h4)
            *(float4*)&dst[h4 * 4] = make_float4(o[h4*4], o[h4*4+1], o[h4*4+2], o[h4*4+3]);
        dst[HH] = 0.5f * sq;
        #pragma unroll
        for (int h = 0; h < HH; ++h) {
            float a = 0.0f;
            #pragma unroll
            for (int j = 0; j < HH; ++j) a += o[j] * We[(HH + j) * HH + h];
            proj[tid][h] = a;
        }
    } else if (tid < NSV + HH) {
        int j = tid - NSV;
        float a = 0.0f;
        #pragma unroll
        for (int h = 0; h < HH; ++h)
            a += (We[j * HH + h] - We[(HH + j) * HH + h]) * Wo[h];
        ucS[j] = a;
    } else if (tid == NSV + HH) {
        float a = bo[0];
        #pragma unroll
        for (int h = 0; h < HH; ++h) a += be[h] * Wo[h];
        ucS[HH] = a;
    }

    // ---- phase B: track MLP (both halves compute their track) ----
    float tf[HH], htsq;
    vf2 ntfp[8];
    {
        const float* xp = x_trk + (size_t)(b * NTRK + tl) * 8;
        float x[8];
        *(float4*)&x[0] = *(const float4*)&xp[0];
        *(float4*)&x[4] = *(const float4*)&xp[4];
        float hb[HH];
        #pragma unroll
        for (int h = 0; h < HH; ++h) {
            float a = b1t[h];
            #pragma unroll
            for (int i = 0; i < 8; ++i) a += x[i] * W1t[i * HH + h];
            hb[h] = elu_f(a);
        }
        float sq = 0.0f;
        #pragma unroll
        for (int h2 = 0; h2 < HH; ++h2) {
            float a = b2t[h2];
            #pragma unroll
            for (int h = 0; h < HH; ++h) a += hb[h] * W2t[h * HH + h2];
            tf[h2] = a;
            sq += a * a;
        }
        htsq = 0.5f * sq;
        #pragma unroll
        for (int j = 0; j < 8; ++j) {
            vf2 t; t.x = -tf[2 * j]; t.y = -tf[2 * j + 1];
            ntfp[j] = t;
        }
    }

    unsigned k[KK];
    #pragma unroll
    for (int q = 0; q < KK; ++q) k[q] = 0xFFFFFFFFu;

    __syncthreads();   // rows drained to L2; proj/uc staged

    // ---- kNN scan of this half's 64 rows: scalar loads, depth-2 pipeline ----
    const int sbase = sh * 64;
    const float* rp = svr + (size_t)(b * NSV + sbase) * RSTR;

    vf2 pa[8], pb[8]; float ha, hbv;

    #define LOADROW(buf, hv, idx)                                      \
        do {                                                           \
            const float* _r = rp + (size_t)(idx) * RSTR;               \
            _Pragma("unroll")                                          \
            for (int _j = 0; _j < 8; ++_j)                             \
                buf[_j] = *(const vf2*)(_r + 2 * _j);                  \
            hv = _r[HH];                                               \
        } while (0)

    #define BODY(buf, hv, idx)                                         \
        do {                                                           \
            vf2 a0 = ntfp[0] * buf[0];                                 \
            vf2 a1 = ntfp[1] * buf[1];                                 \
            vf2 a2 = ntfp[2] * buf[2];                                 \
            vf2 a3 = ntfp[3] * buf[3];                                 \
            a0 = __builtin_elementwise_fma(ntfp[4], buf[4], a0);       \
            a1 = __builtin_elementwise_fma(ntfp[5], buf[5], a1);       \
            a2 = __builtin_elementwise_fma(ntfp[6], buf[6], a2);       \
            a3 = __builtin_elementwise_fma(ntfp[7], buf[7], a3);       \
            a0 = a0 + a1; a2 = a2 + a3; a0 = a0 + a2;                  \
            float e = fmaxf((htsq + hv) + (a0.x + a0.y), 0.0f);        \
            unsigned v = (__float_as_uint(e) & 0xFFFFFF80u)            \
                         | (unsigned)(sbase + (idx));                  \
            unsigned nk0 = umin_u(v, k[0]);                            \
            unsigned nk1 = med3u(v, k[0], k[1]);                       \
            unsigned nk2 = med3u(v, k[1], k[2]);                       \
            unsigned nk3 = med3u(v, k[2], k[3]);                       \
            unsigned nk4 = med3u(v, k[3], k[4]);                       \
            unsigned nk5 = med3u(v, k[4], k[5]);                       \
            unsigned nk6 = med3u(v, k[5], k[6]);                       \
            unsigned nk7 = med3u(v, k[6], k[7]);                       \
            k[0] = nk0; k[1] = nk1; k[2] = nk2; k[3] = nk3;            \
            k[4] = nk4; k[5] = nk5; k[6] = nk6; k[7] = nk7;            \
        } while (0)

    LOADROW(pa, ha, 0);
    LOADROW(pb, hbv, 1);
    for (int s = 0; s < 64 - 2; s += 2) {
        BODY(pa, ha, s);
        LOADROW(pa, ha, s + 2);
        BODY(pb, hbv, s + 1);
        LOADROW(pb, hbv, s + 3);
    }
    BODY(pa, ha, 62);
    BODY(pb, hbv, 63);

    #undef LOADROW
    #undef BODY

    // ---- publish sorted list, merge with partner half ----
    #pragma unroll
    for (int q = 0; q < KK; ++q) kbuf[tl][sh * 8 + q] = k[q];
    __syncthreads();

    unsigned m[KK];
    {
        const unsigned* pk = &kbuf[tl][(sh ^ 1) * 8];
        #pragma unroll
        for (int i = 0; i < KK; ++i) m[i] = umin_u(k[i], pk[7 - i]);
    }

    // ---- epilogue: acc = c0 + tf.u + sum_h max_k(proj)[h]*Wo[h] ----
    float local;
    {
        float acc = ucS[HH];
        #pragma unroll
        for (int j = 0; j < HH; ++j) acc = fmaf(tf[j], ucS[j], acc);

        float mx[HH];
        #pragma unroll
        for (int h = 0; h < HH; ++h) mx[h] = -INFINITY;
        #pragma unroll
        for (int q = 0; q < KK; ++q) {
            const float* pr = &proj[m[q] & 127u][0];
            #pragma unroll
            for (int h4 = 0; h4 < 4; ++h4) {
                float4 p = *(const float4*)&pr[h4 * 4];
                mx[h4 * 4 + 0] = fmaxf(mx[h4 * 4 + 0], p.x);
                mx[h4 * 4 + 1] = fmaxf(mx[h4 * 4 + 1], p.y);
                mx[h4 * 4 + 2] = fmaxf(mx[h4 * 4 + 2], p.z);
                mx[h4 * 4 + 3] = fmaxf(mx[h4 * 4 + 3], p.w);
            }
        }
        #pragma unroll
        for (int h = 0; h < HH; ++h) acc = fmaf(mx[h], Wo[h], acc);
        local = 1.0f / (1.0f + expf(-acc));   // each track counted twice
    }

    // ---- block mean-pool over 1024 values (= 512 tracks x 2) ----
    #pragma unroll
    for (int off = 32; off > 0; off >>= 1)
        local += __shfl_down(local, off, 64);
    if ((tid & 63) == 0) sred[tid >> 6] = local;
    __syncthreads();
    if (tid == 0) {
        float tot = 0.0f;
        #pragma unroll
        for (int w = 0; w < TPB / 64; ++w) tot += sred[w];
        out[b]      = tot * (1.0f / (2 * NTRK));
        out[BB + b] = (float)b;
    }
}

extern "C" void kernel_launch(void* const* d_in, const int* in_sizes, int n_in,
                              void* d_out, int out_size, void* d_ws, size_t ws_size,
                              hipStream_t stream) {
    const float* x_sv  = (const float*)d_in[0];
    const float* x_trk = (const float*)d_in[1];
    const float* W1s = (const float*)d_in[4];
    const float* b1s = (const float*)d_in[5];
    const float* W2s = (const float*)d_in[6];
    const float* b2s = (const float*)d_in[7];
    const float* W1t = (const float*)d_in[8];
    const float* b1t = (const float*)d_in[9];
    const float* W2t = (const float*)d_in[10];
    const float* b2t = (const float*)d_in[11];
    const float* We  = (const float*)d_in[12];
    const float* be  = (const float*)d_in[13];
    const float* Wo  = (const float*)d_in[14];
    const float* bo  = (const float*)d_in[15];
    float* out = (float*)d_out;

    float* rows = (float*)d_ws;      // 512*128*20 floats ≈ 5.2 MB

    fused_all<<<BB, TPB, 0, stream>>>(x_sv, x_trk,
                                      W1s, b1s, W2s, b2s,
                                      W1t, b1t, W2t, b2t,
                                      We, be, Wo, bo,
                                      rows, rows, out);
}